// Round 4
// baseline (7994.801 us; speedup 1.0000x reference)
//
#include <hip/hip_runtime.h>
#include <math.h>

#define TT 512
#define BB 256
#define OBS 128
#define ACT 32
#define HID 512

typedef unsigned short u16;
typedef unsigned int u32;
typedef __attribute__((ext_vector_type(8))) short bf16x8;  // 8 bf16 = 4 VGPRs
typedef __attribute__((ext_vector_type(4))) float f32x4;

__device__ __forceinline__ u16 f2bf(float v) {
  u32 u = __float_as_uint(v);
  u = (u + 0x7fff + ((u >> 16) & 1)) >> 16;  // RNE
  return (u16)u;
}

// ---------------- init / setup kernels ----------------

__global__ void k_init(double* acc, int* bars, u32* zb) {
  int tid = threadIdx.x;
  if (tid == 0) acc[0] = 0.0;
  if (tid < 16) bars[tid * 64] = 0;   // counters padded 256 B apart
  zb[tid] = 0;                        // 256 u32 = 1 KB zero buffer
}

// dst bf16 [Mp][Kp] = zero-padded convert of src fp32 [M][K]   (head weights)
__global__ void k_convert_pad(const float* __restrict__ src, u16* __restrict__ dst,
                              int M, int K, int Mp, int Kp) {
  const int n = Mp * Kp;
  for (int idx = blockIdx.x * blockDim.x + threadIdx.x; idx < n;
       idx += gridDim.x * blockDim.x) {
    int m = idx / Kp, k = idx - m * Kp;
    float v = (m < M && k < K) ? src[(size_t)m * K + k] : 0.f;
    dst[idx] = f2bf(v);
  }
}

// Build recurrence weight arrays:
// Wr/Wz [512][704]: [whh_gate | wih_gate | 0pad32]; Wnh [512][512]; Wni [512][192];
// bias4 [4][512]: r: bih+bhh, z: bih+bhh, n_i: bih, n_h: bhh
__global__ void k_prep_w(const float* __restrict__ w_ih, const float* __restrict__ w_hh,
                         const float* __restrict__ b_ih, const float* __restrict__ b_hh,
                         u16* __restrict__ Wr, u16* __restrict__ Wz,
                         u16* __restrict__ Wnh, u16* __restrict__ Wni,
                         float* __restrict__ bias4) {
  const int stride = gridDim.x * blockDim.x;
  const int t0 = blockIdx.x * blockDim.x + threadIdx.x;
  for (int idx = t0; idx < 512 * 704; idx += stride) {
    int j = idx / 704, k = idx - j * 704;
    float vr, vz;
    if (k < 512)      { vr = w_hh[(size_t)j * 512 + k];        vz = w_hh[(size_t)(512 + j) * 512 + k]; }
    else if (k < 672) { vr = w_ih[(size_t)j * 160 + (k - 512)]; vz = w_ih[(size_t)(512 + j) * 160 + (k - 512)]; }
    else              { vr = 0.f; vz = 0.f; }
    Wr[idx] = f2bf(vr); Wz[idx] = f2bf(vz);
  }
  for (int idx = t0; idx < 512 * 512; idx += stride) {
    int j = idx >> 9, k = idx & 511;
    Wnh[idx] = f2bf(w_hh[(size_t)(1024 + j) * 512 + k]);
  }
  for (int idx = t0; idx < 512 * 192; idx += stride) {
    int j = idx / 192, k = idx - j * 192;
    Wni[idx] = f2bf(k < 160 ? w_ih[(size_t)(1024 + j) * 160 + k] : 0.f);
  }
  for (int idx = t0; idx < 2048; idx += stride) {
    int g = idx >> 9, j = idx & 511;
    float v = (g == 0) ? b_ih[j] + b_hh[j]
            : (g == 1) ? b_ih[512 + j] + b_hh[512 + j]
            : (g == 2) ? b_ih[1024 + j] : b_hh[1024 + j];
    bias4[idx] = v;
  }
}

// Xb [T*B][160] bf16: row (t,b) = t==0 ? [obs[0],0] : [obs[t-1], action[t-1]]
__global__ void k_pack_x(const float* __restrict__ obs, const float* __restrict__ action,
                         u16* __restrict__ Xb) {
  const int n = TT * BB * 160;
  for (int idx = blockIdx.x * blockDim.x + threadIdx.x; idx < n;
       idx += gridDim.x * blockDim.x) {
    int rr = idx / 160, cc = idx - rr * 160;
    int t = rr / BB, b = rr - t * BB;
    float v;
    if (t == 0) v = (cc < OBS) ? obs[(size_t)b * OBS + cc] : 0.f;
    else        v = (cc < OBS) ? obs[((size_t)(t - 1) * BB + b) * OBS + cc]
                               : action[((size_t)(t - 1) * BB + b) * ACT + (cc - OBS)];
    Xb[idx] = f2bf(v);
  }
}

// ---------------- persistent GRU recurrence ----------------
// Grid (16 jt, 16 bt) = 256 blocks, 1/CU (LDS-forced). Steps t0..t0+TC-1.
// Block (jt,bt): 16 batch rows x 32 hidden cols; 8 output tiles (r0,r1,z0,z1,nh0,nh1,ni0,ni1).
// Weights LDS-resident for the whole launch. Per-bt 16-block spin barrier per step.
__global__ __launch_bounds__(256, 1) void k_gru_seq(
    const u16* __restrict__ Wr, const u16* __restrict__ Wz,
    const u16* __restrict__ Wnh, const u16* __restrict__ Wni,
    const float* __restrict__ bias4, const u16* __restrict__ Xb,
    u16* __restrict__ hs,          // [TC][BB][512] bf16 (slot TC-1 carries across launches)
    float* __restrict__ h32c,      // [BB][512] fp32 carry
    const u16* __restrict__ zb,    // 1 KB zeros
    int* __restrict__ bars,        // 16 counters, stride 64 ints
    int t0, int TC)
{
  __shared__ u16 Bs[67584];                    // 132 KB: Br|Bz|Bnh|Bni (chunk-swizzled)
  __shared__ __align__(16) char scratch[22528];  // A tile (22528 B) / red[2][8][16][16] (16384 B)
  u16* As = (u16*)scratch;
  float* red = (float*)scratch;

  const int jt = blockIdx.x, bt = blockIdx.y;
  const int tid = threadIdx.x, w = tid >> 6, lane = tid & 63;
  const int m16 = lane & 15, q = lane >> 4;

  // ---- stage weights once (8448 16B-chunks = 132 wave-instrs) ----
  for (int i = w; i < 132; i += 4) {
    int fc = i * 64 + lane;
    const u16* g;
    if (fc < 5632) {                 // Wr / Wz: 88 chunks/row, 704 cols
      int loc = (fc < 2816) ? fc : fc - 2816;
      int jj = loc / 88, c = loc - jj * 88;
      int cg = c ^ (jj & 7);
      const u16* W = (fc < 2816) ? Wr : Wz;
      g = W + ((size_t)(jt * 32 + jj) * 704 + cg * 8);
    } else if (fc < 7680) {          // Wnh: 64 chunks/row, 512 cols
      int loc = fc - 5632;
      int jj = loc >> 6, c = loc & 63;
      int cg = c ^ (jj & 7);
      g = Wnh + ((size_t)(jt * 32 + jj) * 512 + cg * 8);
    } else {                         // Wni: 24 chunks/row, 192 cols
      int loc = fc - 7680;
      int jj = loc / 24, c = loc - jj * 24;
      int cg = c ^ (jj & 7);
      g = Wni + ((size_t)(jt * 32 + jj) * 192 + cg * 8);
    }
    __builtin_amdgcn_global_load_lds((const __attribute__((address_space(1))) u32*)g,
        (__attribute__((address_space(3))) u32*)(Bs + i * 512), 16, 0, 0);
  }

  // ---- per-lane A-stage descriptors (t-independent) ----
  // A: 16 rows x 88 chunks (704 u16/row): [h(64ch) | x(20ch) | pad(4ch)], swizzled
  int aFlag[6]; u32 aOff[6];
  const int nAI = (w < 2) ? 6 : 5;   // 22 instrs: i = w, w+4, ...
  for (int n2 = 0; n2 < 6; ++n2) { aFlag[n2] = 2; aOff[n2] = 0; }
  for (int n2 = 0; n2 < nAI; ++n2) {
    int fc = (w + 4 * n2) * 64 + lane;
    int r = fc / 88, c = fc - r * 88;
    int cg = c ^ (r & 7);
    int b = bt * 16 + r;
    if (cg < 64)      { aFlag[n2] = 0; aOff[n2] = (u32)b * 512 + cg * 8; }
    else if (cg < 84) { aFlag[n2] = 1; aOff[n2] = (u32)b * 160 + (cg - 64) * 8; }
  }

  // ---- epilogue-lane constants: this thread owns (eb, j0) and (eb, j0+1) forever ----
  const int eb = tid >> 4;
  const int j0 = (tid & 15) * 2;
  const int gj = jt * 32 + j0;
  const int gb = bt * 16 + eb;
  const float br0 = bias4[gj],        br1 = bias4[gj + 1];
  const float bz0 = bias4[512 + gj],  bz1 = bias4[512 + gj + 1];
  const float bi0 = bias4[1024 + gj], bi1 = bias4[1024 + gj + 1];
  const float bh0 = bias4[1536 + gj], bh1 = bias4[1536 + gj + 1];
  float hv0 = 0.f, hv1 = 0.f;
  if (t0 > 0) { hv0 = h32c[(size_t)gb * 512 + gj]; hv1 = h32c[(size_t)gb * 512 + gj + 1]; }

  const int ti = j0 >> 4, c0 = j0 & 15;

  for (int s = 0; s < TC; ++s) {
    const int t = t0 + s;
    const int sp = (s == 0) ? TC - 1 : s - 1;
    const u16* hsrc = hs + (size_t)sp * BB * 512;
    const u16* xsrc = Xb + (size_t)t * BB * 160;
    const bool hzero = (t == 0);

    // stage A
    for (int n2 = 0; n2 < nAI; ++n2) {
      const u16* g = (aFlag[n2] == 0) ? (hzero ? zb : hsrc + aOff[n2])
                   : (aFlag[n2] == 1) ? (xsrc + aOff[n2]) : zb;
      __builtin_amdgcn_global_load_lds((const __attribute__((address_space(1))) u32*)g,
          (__attribute__((address_space(3))) u32*)(As + (w + 4 * n2) * 512), 16, 0, 0);
    }
    __syncthreads();  // drains vmcnt (A + first-iter B) before ds_read

    // MFMA: wave w takes ks = w, w+4, ... < 21
    f32x4 acc[8];
#pragma unroll
    for (int ct = 0; ct < 8; ++ct) acc[ct] = (f32x4){0.f, 0.f, 0.f, 0.f};
    for (int ks = w; ks < 21; ks += 4) {
      int cb = ks * 4 + q;
      bf16x8 af = *(const bf16x8*)&As[(size_t)m16 * 704 + (cb ^ (m16 & 7)) * 8];
#pragma unroll
      for (int h2 = 0; h2 < 2; ++h2) {
        int jj = h2 * 16 + m16;
        int sw = (cb ^ (jj & 7)) * 8;
        bf16x8 b0 = *(const bf16x8*)&Bs[(size_t)jj * 704 + sw];
        acc[h2] = __builtin_amdgcn_mfma_f32_16x16x32_bf16(af, b0, acc[h2], 0, 0, 0);
        bf16x8 b1 = *(const bf16x8*)&Bs[22528 + (size_t)jj * 704 + sw];
        acc[2 + h2] = __builtin_amdgcn_mfma_f32_16x16x32_bf16(af, b1, acc[2 + h2], 0, 0, 0);
      }
      if (ks < 16) {
#pragma unroll
        for (int h2 = 0; h2 < 2; ++h2) {
          int jj = h2 * 16 + m16;
          bf16x8 b2 = *(const bf16x8*)&Bs[45056 + (size_t)jj * 512 + (cb ^ (jj & 7)) * 8];
          acc[4 + h2] = __builtin_amdgcn_mfma_f32_16x16x32_bf16(af, b2, acc[4 + h2], 0, 0, 0);
        }
      } else {
        int cb2 = (ks - 16) * 4 + q;
#pragma unroll
        for (int h2 = 0; h2 < 2; ++h2) {
          int jj = h2 * 16 + m16;
          bf16x8 b3 = *(const bf16x8*)&Bs[61440 + (size_t)jj * 192 + (cb2 ^ (jj & 7)) * 8];
          acc[6 + h2] = __builtin_amdgcn_mfma_f32_16x16x32_bf16(af, b3, acc[6 + h2], 0, 0, 0);
        }
      }
    }
    __syncthreads();  // all A/B frag reads done before red overwrites scratch

    // cross-wave reduce, 2 rounds: w0,w1 write; w2,w3 accumulate
    {
      float* myred = red + (w & 1) * 2048;
      if (w < 2) {
#pragma unroll
        for (int ct = 0; ct < 8; ++ct)
#pragma unroll
          for (int p = 0; p < 4; ++p) myred[ct * 256 + (q * 4 + p) * 16 + m16] = acc[ct][p];
      }
      __syncthreads();
      if (w >= 2) {
#pragma unroll
        for (int ct = 0; ct < 8; ++ct)
#pragma unroll
          for (int p = 0; p < 4; ++p) {
            int o = ct * 256 + (q * 4 + p) * 16 + m16;
            myred[o] += acc[ct][p];
          }
      }
      __syncthreads();
    }

    // gates + h update (thread owns (eb, j0), (eb, j0+1))
    {
#define RD(ctt, cc) (red[(ctt)*256 + eb*16 + (cc)] + red[2048 + (ctt)*256 + eb*16 + (cc)])
      float rs0 = RD(ti, c0),     rs1 = RD(ti, c0 + 1);
      float zs0 = RD(2 + ti, c0), zs1 = RD(2 + ti, c0 + 1);
      float nh0 = RD(4 + ti, c0), nh1 = RD(4 + ti, c0 + 1);
      float ni0 = RD(6 + ti, c0), ni1 = RD(6 + ti, c0 + 1);
#undef RD
      float r0 = 1.f / (1.f + expf(-(rs0 + br0)));
      float z0 = 1.f / (1.f + expf(-(zs0 + bz0)));
      float n0 = tanhf(ni0 + bi0 + r0 * (nh0 + bh0));
      float h0 = (1.f - z0) * n0 + z0 * hv0;
      float r1 = 1.f / (1.f + expf(-(rs1 + br1)));
      float z1 = 1.f / (1.f + expf(-(zs1 + bz1)));
      float n1 = tanhf(ni1 + bi1 + r1 * (nh1 + bh1));
      float h1 = (1.f - z1) * n1 + z1 * hv1;
      hv0 = h0; hv1 = h1;
      u32 pk = (u32)f2bf(h0) | ((u32)f2bf(h1) << 16);
      *(u32*)&hs[((size_t)s * BB + gb) * 512 + gj] = pk;
    }

    // group barrier (16 blocks sharing bt)
    __syncthreads();  // vmcnt(0): all waves' hs stores are in L2
    if (tid == 0) {
      __threadfence();  // agent release: write back L2 for cross-XCD readers
      __hip_atomic_fetch_add(&bars[bt * 64], 1, __ATOMIC_RELEASE, __HIP_MEMORY_SCOPE_AGENT);
      const int target = 16 * (t + 1);
      while (__hip_atomic_load(&bars[bt * 64], __ATOMIC_RELAXED, __HIP_MEMORY_SCOPE_AGENT) < target)
        __builtin_amdgcn_s_sleep(1);
      (void)__hip_atomic_load(&bars[bt * 64], __ATOMIC_ACQUIRE, __HIP_MEMORY_SCOPE_AGENT);
    }
    __syncthreads();
  }

  h32c[(size_t)gb * 512 + gj] = hv0;
  h32c[(size_t)gb * 512 + gj + 1] = hv1;
}

// ---------------- MFMA GEMM (heads) ----------------
// C[N][M] = act( A[N][K] @ B[Mp][K]^T + bias[M] ); K mult of 64, N mult of 128.
__global__ __launch_bounds__(256) void k_mfma_gemm(
    const u16* __restrict__ A, const u16* __restrict__ B,
    const float* __restrict__ bias,
    float* __restrict__ outf, u16* __restrict__ outb,
    int N, int K, int M, int act)
{
  __shared__ u16 As[128 * 64];
  __shared__ u16 Bs[128 * 64];
  const int bn = blockIdx.y * 128;
  const int bm = blockIdx.x * 128;
  const int tid = threadIdx.x;
  const int w = tid >> 6, lane = tid & 63;
  const int wr = w >> 1, wc = w & 1;

  f32x4 acc[4][4];
#pragma unroll
  for (int i = 0; i < 4; ++i)
#pragma unroll
    for (int j = 0; j < 4; ++j) acc[i][j] = (f32x4){0.f, 0.f, 0.f, 0.f};

  const int lr8 = lane >> 3;
  const int lc8 = lane & 7;

  for (int kt = 0; kt < K; kt += 64) {
    __syncthreads();
#pragma unroll
    for (int i = 0; i < 4; ++i) {
      int r0 = (w * 4 + i) * 8;
      int r = r0 + lr8;
      int c = lc8 ^ (r & 7);
      const u16* ga = A + (size_t)(bn + r) * K + kt + c * 8;
      const u16* gb = B + (size_t)(bm + r) * K + kt + c * 8;
      __builtin_amdgcn_global_load_lds((const __attribute__((address_space(1))) u32*)ga,
                                       (__attribute__((address_space(3))) u32*)(As + r0 * 64), 16, 0, 0);
      __builtin_amdgcn_global_load_lds((const __attribute__((address_space(1))) u32*)gb,
                                       (__attribute__((address_space(3))) u32*)(Bs + r0 * 64), 16, 0, 0);
    }
    __syncthreads();

    const int m16 = lane & 15, q = lane >> 4;
#pragma unroll
    for (int kk = 0; kk < 2; ++kk) {
      bf16x8 af[4], bfr[4];
#pragma unroll
      for (int i = 0; i < 4; ++i) {
        int ra = wr * 64 + i * 16 + m16;
        af[i] = *(const bf16x8*)&As[ra * 64 + ((kk * 4 + q) ^ (ra & 7)) * 8];
        int rb = wc * 64 + i * 16 + m16;
        bfr[i] = *(const bf16x8*)&Bs[rb * 64 + ((kk * 4 + q) ^ (rb & 7)) * 8];
      }
#pragma unroll
      for (int i = 0; i < 4; ++i)
#pragma unroll
        for (int j = 0; j < 4; ++j)
          acc[i][j] = __builtin_amdgcn_mfma_f32_16x16x32_bf16(af[i], bfr[j], acc[i][j], 0, 0, 0);
    }
  }

  const int m16 = lane & 15, q = lane >> 4;
#pragma unroll
  for (int i = 0; i < 4; ++i) {
#pragma unroll
    for (int j = 0; j < 4; ++j) {
      int col = bm + wc * 64 + j * 16 + m16;
      if (col >= M) continue;
      float bs = bias[col];
#pragma unroll
      for (int p = 0; p < 4; ++p) {
        int row = bn + wr * 64 + i * 16 + q * 4 + p;
        float v = acc[i][j][p] + bs;
        if (act) v = (v > 0.f) ? v : expm1f(v);
        if (outf) outf[(size_t)row * M + col] = v;
        else      outb[(size_t)row * M + col] = f2bf(v);
      }
    }
  }
}

// ---------------- loss ----------------
__global__ __launch_bounds__(256) void k_loss(
    const float* __restrict__ obs, const float* __restrict__ action,
    const float* __restrict__ p_obs, const float* __restrict__ p_act,
    const float* __restrict__ p_rew, double* __restrict__ acc)
{
  const long long n1 = (long long)TT * BB * OBS;
  const long long n2 = (long long)TT * BB * ACT;
  const long long n  = n1 + n2 + n2;
  const float C = 0.91893853320467274178f;  // 0.5*ln(2*pi)
  double s = 0.0;
  for (long long idx = (long long)blockIdx.x * blockDim.x + threadIdx.x; idx < n;
       idx += (long long)gridDim.x * blockDim.x) {
    float d;
    if (idx < n1) {
      d = obs[idx] - p_obs[idx];
    } else if (idx < n1 + n2) {
      long long i = idx - n1;
      d = action[i] - p_act[i];
    } else {
      long long i = idx - n1 - n2;
      d = action[i] - p_rew[i >> 5];
    }
    s += (double)(0.5f * d * d + C);
  }
  __shared__ double red[256];
  red[threadIdx.x] = s;
  __syncthreads();
  for (int off = 128; off > 0; off >>= 1) {
    if ((int)threadIdx.x < off) red[threadIdx.x] += red[threadIdx.x + off];
    __syncthreads();
  }
  if (threadIdx.x == 0) atomicAdd(acc, red[0]);
}

__global__ void k_finalize(const double* __restrict__ acc, float* __restrict__ out) {
  if (threadIdx.x == 0) out[0] = (float)(acc[0] / (double)(TT * BB));
}

// ---------------- launch ----------------

extern "C" void kernel_launch(void* const* d_in, const int* in_sizes, int n_in,
                              void* d_out, int out_size, void* d_ws, size_t ws_size,
                              hipStream_t stream) {
  const float* obs    = (const float*)d_in[0];
  const float* action = (const float*)d_in[1];
  const float* w_ih = (const float*)d_in[3];
  const float* w_hh = (const float*)d_in[4];
  const float* b_ih = (const float*)d_in[5];
  const float* b_hh = (const float*)d_in[6];
  const float* hw[9] = {(const float*)d_in[7],  (const float*)d_in[9],  (const float*)d_in[11],
                        (const float*)d_in[13], (const float*)d_in[15], (const float*)d_in[17],
                        (const float*)d_in[19], (const float*)d_in[21], (const float*)d_in[23]};
  const float* hb[9] = {(const float*)d_in[8],  (const float*)d_in[10], (const float*)d_in[12],
                        (const float*)d_in[14], (const float*)d_in[16], (const float*)d_in[18],
                        (const float*)d_in[20], (const float*)d_in[22], (const float*)d_in[24]};
  const int hM[9]  = {512, 512, 128, 512, 512, 32, 512, 512, 1};
  const int hMp[9] = {512, 512, 128, 512, 512, 128, 512, 512, 128};

  float* out     = (float*)d_out;
  float* pre_obs = out + 1;
  float* pre_act = pre_obs + (size_t)TT * BB * OBS;
  float* pre_rew = pre_act + (size_t)TT * BB * ACT;

  // ---- workspace ----
  char* ws = (char*)d_ws;
  size_t off = 0;
  auto alloc = [&](size_t bytes) { void* p = ws + off; off = (off + bytes + 255) & ~(size_t)255; return p; };
  double* acc  = (double*)alloc(256);
  int* bars    = (int*)alloc(16 * 256);           // padded counters
  u32* zerobuf = (u32*)alloc(1024);
  u16* Wr  = (u16*)alloc((size_t)512 * 704 * 2);
  u16* Wz  = (u16*)alloc((size_t)512 * 704 * 2);
  u16* Wnh = (u16*)alloc((size_t)512 * 512 * 2);
  u16* Wni = (u16*)alloc((size_t)512 * 192 * 2);
  float* bias4 = (float*)alloc(2048 * 4);
  u16* headb[9];
  for (int i = 0; i < 9; ++i) headb[i] = (u16*)alloc((size_t)hMp[i] * 512 * 2);
  float* h32c = (float*)alloc((size_t)BB * 512 * 4);
  u16* Xb     = (u16*)alloc((size_t)TT * BB * 160 * 2);   // 41.9 MB
  const size_t fixed = off;

  int TC = 512;
  while (TC > 8 && fixed + 3ull * TC * BB * 512 * 2ull + (1u << 20) > ws_size) TC >>= 1;
  u16* hs_chunk = (u16*)alloc((size_t)TC * BB * 512 * 2);
  u16* tmp1b    = (u16*)alloc((size_t)TC * BB * 512 * 2);
  u16* tmp2b    = (u16*)alloc((size_t)TC * BB * 512 * 2);
  const int CH = TC * BB;
  const int NCH = TT / TC;

  // ---- setup ----
  k_init<<<1, 256, 0, stream>>>(acc, bars, zerobuf);
  k_prep_w<<<512, 256, 0, stream>>>(w_ih, w_hh, b_ih, b_hh, Wr, Wz, Wnh, Wni, bias4);
  for (int i = 0; i < 9; ++i)
    k_convert_pad<<<512, 256, 0, stream>>>(hw[i], headb[i], hM[i], 512, hMp[i], 512);
  k_pack_x<<<4096, 256, 0, stream>>>(obs, action, Xb);

  for (int c = 0; c < NCH; ++c) {
    k_gru_seq<<<dim3(16, 16), 256, 0, stream>>>(
        Wr, Wz, Wnh, Wni, bias4, Xb, hs_chunk, h32c, (const u16*)zerobuf, bars, c * TC, TC);
    for (int h = 0; h < 3; ++h) {
      int M2 = hM[h * 3 + 2], Mp2 = hMp[h * 3 + 2];
      float* outp = (h == 0) ? pre_obs + (size_t)c * CH * OBS
                  : (h == 1) ? pre_act + (size_t)c * CH * ACT
                             : pre_rew + (size_t)c * CH;
      k_mfma_gemm<<<dim3(4, CH / 128), 256, 0, stream>>>(
          hs_chunk, headb[h * 3 + 0], hb[h * 3 + 0], nullptr, tmp1b, CH, 512, 512, 1);
      k_mfma_gemm<<<dim3(4, CH / 128), 256, 0, stream>>>(
          tmp1b, headb[h * 3 + 1], hb[h * 3 + 1], nullptr, tmp2b, CH, 512, 512, 1);
      k_mfma_gemm<<<dim3(Mp2 / 128, CH / 128), 256, 0, stream>>>(
          tmp2b, headb[h * 3 + 2], hb[h * 3 + 2], outp, nullptr, CH, 512, M2, 0);
    }
  }

  k_loss<<<2048, 256, 0, stream>>>(obs, action, pre_obs, pre_act, pre_rew, acc);
  k_finalize<<<1, 64, 0, stream>>>(acc, out);
}

// Round 5
// 3894.082 us; speedup vs baseline: 2.0531x; 2.0531x over previous
//
#include <hip/hip_runtime.h>
#include <math.h>

#define TT 512
#define BB 256
#define OBS 128
#define ACT 32
#define HID 512
#define AUX_SC 0x11  // SC0|SC1 cache policy: device-scope coherent (bypass L1/L2, read LLC)

typedef unsigned short u16;
typedef unsigned int u32;
typedef __attribute__((ext_vector_type(8))) short bf16x8;  // 8 bf16 = 4 VGPRs
typedef __attribute__((ext_vector_type(4))) float f32x4;

__device__ __forceinline__ u16 f2bf(float v) {
  u32 u = __float_as_uint(v);
  u = (u + 0x7fff + ((u >> 16) & 1)) >> 16;  // RNE
  return (u16)u;
}

// ---------------- init / setup kernels ----------------

__global__ void k_init(double* acc, int* bars, u32* zb) {
  int tid = threadIdx.x;
  if (tid == 0) acc[0] = 0.0;
  if (tid < 16) bars[tid * 64] = 0;   // counters padded 256 B apart
  zb[tid] = 0;                        // 256 u32 = 1 KB zero buffer
}

// dst bf16 [Mp][Kp] = zero-padded convert of src fp32 [M][K]   (head weights)
__global__ void k_convert_pad(const float* __restrict__ src, u16* __restrict__ dst,
                              int M, int K, int Mp, int Kp) {
  const int n = Mp * Kp;
  for (int idx = blockIdx.x * blockDim.x + threadIdx.x; idx < n;
       idx += gridDim.x * blockDim.x) {
    int m = idx / Kp, k = idx - m * Kp;
    float v = (m < M && k < K) ? src[(size_t)m * K + k] : 0.f;
    dst[idx] = f2bf(v);
  }
}

// Build recurrence weight arrays:
// Wr/Wz [512][704]: [whh_gate | wih_gate | 0pad32]; Wnh [512][512]; Wni [512][192];
// bias4 [4][512]: r: bih+bhh, z: bih+bhh, n_i: bih, n_h: bhh
__global__ void k_prep_w(const float* __restrict__ w_ih, const float* __restrict__ w_hh,
                         const float* __restrict__ b_ih, const float* __restrict__ b_hh,
                         u16* __restrict__ Wr, u16* __restrict__ Wz,
                         u16* __restrict__ Wnh, u16* __restrict__ Wni,
                         float* __restrict__ bias4) {
  const int stride = gridDim.x * blockDim.x;
  const int t0 = blockIdx.x * blockDim.x + threadIdx.x;
  for (int idx = t0; idx < 512 * 704; idx += stride) {
    int j = idx / 704, k = idx - j * 704;
    float vr, vz;
    if (k < 512)      { vr = w_hh[(size_t)j * 512 + k];        vz = w_hh[(size_t)(512 + j) * 512 + k]; }
    else if (k < 672) { vr = w_ih[(size_t)j * 160 + (k - 512)]; vz = w_ih[(size_t)(512 + j) * 160 + (k - 512)]; }
    else              { vr = 0.f; vz = 0.f; }
    Wr[idx] = f2bf(vr); Wz[idx] = f2bf(vz);
  }
  for (int idx = t0; idx < 512 * 512; idx += stride) {
    int j = idx >> 9, k = idx & 511;
    Wnh[idx] = f2bf(w_hh[(size_t)(1024 + j) * 512 + k]);
  }
  for (int idx = t0; idx < 512 * 192; idx += stride) {
    int j = idx / 192, k = idx - j * 192;
    Wni[idx] = f2bf(k < 160 ? w_ih[(size_t)(1024 + j) * 160 + k] : 0.f);
  }
  for (int idx = t0; idx < 2048; idx += stride) {
    int g = idx >> 9, j = idx & 511;
    float v = (g == 0) ? b_ih[j] + b_hh[j]
            : (g == 1) ? b_ih[512 + j] + b_hh[512 + j]
            : (g == 2) ? b_ih[1024 + j] : b_hh[1024 + j];
    bias4[idx] = v;
  }
}

// Xb [T*B][160] bf16: row (t,b) = t==0 ? [obs[0],0] : [obs[t-1], action[t-1]]
__global__ void k_pack_x(const float* __restrict__ obs, const float* __restrict__ action,
                         u16* __restrict__ Xb) {
  const int n = TT * BB * 160;
  for (int idx = blockIdx.x * blockDim.x + threadIdx.x; idx < n;
       idx += gridDim.x * blockDim.x) {
    int rr = idx / 160, cc = idx - rr * 160;
    int t = rr / BB, b = rr - t * BB;
    float v;
    if (t == 0) v = (cc < OBS) ? obs[(size_t)b * OBS + cc] : 0.f;
    else        v = (cc < OBS) ? obs[((size_t)(t - 1) * BB + b) * OBS + cc]
                               : action[((size_t)(t - 1) * BB + b) * ACT + (cc - OBS)];
    Xb[idx] = f2bf(v);
  }
}

// ---------------- persistent GRU recurrence ----------------
// Grid (16 jt, 16 bt) = 256 blocks, 1/CU (LDS-forced). Steps t0..t0+TC-1.
// h crosses blocks via LLC only: A-stage loads use SC0|SC1, h stores are relaxed
// agent atomics (write-through), barrier is fence-free relaxed atomics.
// NO wbl2/inv in the loop — weights/Xb/bias stay L2-resident.
__global__ __launch_bounds__(256, 1) void k_gru_seq(
    const u16* __restrict__ Wr, const u16* __restrict__ Wz,
    const u16* __restrict__ Wnh, const u16* __restrict__ Wni,
    const float* __restrict__ bias4, const u16* __restrict__ Xb,
    u16* __restrict__ hs,          // [TC][BB][512] bf16 (slot TC-1 carries across launches)
    float* __restrict__ h32c,      // [BB][512] fp32 carry
    const u16* __restrict__ zb,    // 1 KB zeros
    int* __restrict__ bars,        // 16 counters, stride 64 ints
    int t0, int TC)
{
  __shared__ u16 Bs[67584];                    // 132 KB: Br|Bz|Bnh|Bni (chunk-swizzled)
  __shared__ __align__(16) char scratch[22528];  // A tile (22528 B) / red[2][8][16][16] (16384 B)
  u16* As = (u16*)scratch;
  float* red = (float*)scratch;

  const int jt = blockIdx.x, bt = blockIdx.y;
  const int tid = threadIdx.x, w = tid >> 6, lane = tid & 63;
  const int m16 = lane & 15, q = lane >> 4;

  // ---- stage weights once (8448 16B-chunks = 132 wave-instrs), normal cached ----
  for (int i = w; i < 132; i += 4) {
    int fc = i * 64 + lane;
    const u16* g;
    if (fc < 5632) {                 // Wr / Wz: 88 chunks/row, 704 cols
      int loc = (fc < 2816) ? fc : fc - 2816;
      int jj = loc / 88, c = loc - jj * 88;
      int cg = c ^ (jj & 7);
      const u16* W = (fc < 2816) ? Wr : Wz;
      g = W + ((size_t)(jt * 32 + jj) * 704 + cg * 8);
    } else if (fc < 7680) {          // Wnh: 64 chunks/row, 512 cols
      int loc = fc - 5632;
      int jj = loc >> 6, c = loc & 63;
      int cg = c ^ (jj & 7);
      g = Wnh + ((size_t)(jt * 32 + jj) * 512 + cg * 8);
    } else {                         // Wni: 24 chunks/row, 192 cols
      int loc = fc - 7680;
      int jj = loc / 24, c = loc - jj * 24;
      int cg = c ^ (jj & 7);
      g = Wni + ((size_t)(jt * 32 + jj) * 192 + cg * 8);
    }
    __builtin_amdgcn_global_load_lds((const __attribute__((address_space(1))) u32*)g,
        (__attribute__((address_space(3))) u32*)(Bs + i * 512), 16, 0, 0);
  }

  // ---- per-lane A-stage descriptors (t-independent) ----
  // A: 16 rows x 88 chunks (704 u16/row): [h(64ch) | x(20ch) | pad(4ch)], swizzled
  int aFlag[6]; u32 aOff[6];
  const int nAI = (w < 2) ? 6 : 5;   // 22 instrs: i = w, w+4, ...
  for (int n2 = 0; n2 < 6; ++n2) { aFlag[n2] = 2; aOff[n2] = 0; }
  for (int n2 = 0; n2 < nAI; ++n2) {
    int fc = (w + 4 * n2) * 64 + lane;
    int r = fc / 88, c = fc - r * 88;
    int cg = c ^ (r & 7);
    int b = bt * 16 + r;
    if (cg < 64)      { aFlag[n2] = 0; aOff[n2] = (u32)b * 512 + cg * 8; }
    else if (cg < 84) { aFlag[n2] = 1; aOff[n2] = (u32)b * 160 + (cg - 64) * 8; }
  }

  // ---- epilogue-lane constants: this thread owns (eb, j0) and (eb, j0+1) forever ----
  const int eb = tid >> 4;
  const int j0 = (tid & 15) * 2;
  const int gj = jt * 32 + j0;
  const int gb = bt * 16 + eb;
  const float br0 = bias4[gj],        br1 = bias4[gj + 1];
  const float bz0 = bias4[512 + gj],  bz1 = bias4[512 + gj + 1];
  const float bi0 = bias4[1024 + gj], bi1 = bias4[1024 + gj + 1];
  const float bh0 = bias4[1536 + gj], bh1 = bias4[1536 + gj + 1];
  float hv0 = 0.f, hv1 = 0.f;
  if (t0 > 0) { hv0 = h32c[(size_t)gb * 512 + gj]; hv1 = h32c[(size_t)gb * 512 + gj + 1]; }

  const int ti = j0 >> 4, c0 = j0 & 15;

  for (int s = 0; s < TC; ++s) {
    const int t = t0 + s;
    const int sp = (s == 0) ? TC - 1 : s - 1;
    const u16* hsrc = hs + (size_t)sp * BB * 512;
    const u16* xsrc = Xb + (size_t)t * BB * 160;
    const bool hzero = (t == 0);

    // stage A: h reads device-coherent (SC0|SC1 -> LLC), x/pad likewise (cheap, uniform)
    for (int n2 = 0; n2 < nAI; ++n2) {
      const u16* g = (aFlag[n2] == 0) ? (hzero ? zb : hsrc + aOff[n2])
                   : (aFlag[n2] == 1) ? (xsrc + aOff[n2]) : zb;
      __builtin_amdgcn_global_load_lds((const __attribute__((address_space(1))) u32*)g,
          (__attribute__((address_space(3))) u32*)(As + (w + 4 * n2) * 512), 16, 0, AUX_SC);
    }
    __syncthreads();  // drains vmcnt (A + first-iter B) before ds_read

    // MFMA: wave w takes ks = w, w+4, ... < 21
    f32x4 acc[8];
#pragma unroll
    for (int ct = 0; ct < 8; ++ct) acc[ct] = (f32x4){0.f, 0.f, 0.f, 0.f};
    for (int ks = w; ks < 21; ks += 4) {
      int cb = ks * 4 + q;
      bf16x8 af = *(const bf16x8*)&As[(size_t)m16 * 704 + (cb ^ (m16 & 7)) * 8];
#pragma unroll
      for (int h2 = 0; h2 < 2; ++h2) {
        int jj = h2 * 16 + m16;
        int sw = (cb ^ (jj & 7)) * 8;
        bf16x8 b0 = *(const bf16x8*)&Bs[(size_t)jj * 704 + sw];
        acc[h2] = __builtin_amdgcn_mfma_f32_16x16x32_bf16(af, b0, acc[h2], 0, 0, 0);
        bf16x8 b1 = *(const bf16x8*)&Bs[22528 + (size_t)jj * 704 + sw];
        acc[2 + h2] = __builtin_amdgcn_mfma_f32_16x16x32_bf16(af, b1, acc[2 + h2], 0, 0, 0);
      }
      if (ks < 16) {
#pragma unroll
        for (int h2 = 0; h2 < 2; ++h2) {
          int jj = h2 * 16 + m16;
          bf16x8 b2 = *(const bf16x8*)&Bs[45056 + (size_t)jj * 512 + (cb ^ (jj & 7)) * 8];
          acc[4 + h2] = __builtin_amdgcn_mfma_f32_16x16x32_bf16(af, b2, acc[4 + h2], 0, 0, 0);
        }
      } else {
        int cb2 = (ks - 16) * 4 + q;
#pragma unroll
        for (int h2 = 0; h2 < 2; ++h2) {
          int jj = h2 * 16 + m16;
          bf16x8 b3 = *(const bf16x8*)&Bs[61440 + (size_t)jj * 192 + (cb2 ^ (jj & 7)) * 8];
          acc[6 + h2] = __builtin_amdgcn_mfma_f32_16x16x32_bf16(af, b3, acc[6 + h2], 0, 0, 0);
        }
      }
    }
    __syncthreads();  // all A/B frag reads done before red overwrites scratch

    // cross-wave reduce, 2 rounds: w0,w1 write; w2,w3 accumulate
    {
      float* myred = red + (w & 1) * 2048;
      if (w < 2) {
#pragma unroll
        for (int ct = 0; ct < 8; ++ct)
#pragma unroll
          for (int p = 0; p < 4; ++p) myred[ct * 256 + (q * 4 + p) * 16 + m16] = acc[ct][p];
      }
      __syncthreads();
      if (w >= 2) {
#pragma unroll
        for (int ct = 0; ct < 8; ++ct)
#pragma unroll
          for (int p = 0; p < 4; ++p) {
            int o = ct * 256 + (q * 4 + p) * 16 + m16;
            myred[o] += acc[ct][p];
          }
      }
      __syncthreads();
    }

    // gates + h update (thread owns (eb, j0), (eb, j0+1))
    {
#define RD(ctt, cc) (red[(ctt)*256 + eb*16 + (cc)] + red[2048 + (ctt)*256 + eb*16 + (cc)])
      float rs0 = RD(ti, c0),     rs1 = RD(ti, c0 + 1);
      float zs0 = RD(2 + ti, c0), zs1 = RD(2 + ti, c0 + 1);
      float nh0 = RD(4 + ti, c0), nh1 = RD(4 + ti, c0 + 1);
      float ni0 = RD(6 + ti, c0), ni1 = RD(6 + ti, c0 + 1);
#undef RD
      float r0 = 1.f / (1.f + expf(-(rs0 + br0)));
      float z0 = 1.f / (1.f + expf(-(zs0 + bz0)));
      float n0 = tanhf(ni0 + bi0 + r0 * (nh0 + bh0));
      float h0 = (1.f - z0) * n0 + z0 * hv0;
      float r1 = 1.f / (1.f + expf(-(rs1 + br1)));
      float z1 = 1.f / (1.f + expf(-(zs1 + bz1)));
      float n1 = tanhf(ni1 + bi1 + r1 * (nh1 + bh1));
      float h1 = (1.f - z1) * n1 + z1 * hv1;
      hv0 = h0; hv1 = h1;
      u32 pk = (u32)f2bf(h0) | ((u32)f2bf(h1) << 16);
      // write-through to LLC (device-coherent), nothing dirty left in L2
      __hip_atomic_store((u32*)&hs[((size_t)s * BB + gb) * 512 + gj], pk,
                         __ATOMIC_RELAXED, __HIP_MEMORY_SCOPE_AGENT);
    }

    // fence-free group barrier (16 blocks sharing bt):
    // __syncthreads drains vmcnt -> all sc1 stores acked at LLC before the flag add.
    __syncthreads();
    if (tid == 0) {
      __hip_atomic_fetch_add(&bars[bt * 64], 1, __ATOMIC_RELAXED, __HIP_MEMORY_SCOPE_AGENT);
      const int target = 16 * (t + 1);
      while (__hip_atomic_load(&bars[bt * 64], __ATOMIC_RELAXED, __HIP_MEMORY_SCOPE_AGENT) < target)
        __builtin_amdgcn_s_sleep(1);
    }
    __syncthreads();
  }

  h32c[(size_t)gb * 512 + gj] = hv0;
  h32c[(size_t)gb * 512 + gj + 1] = hv1;
}

// ---------------- MFMA GEMM (heads) ----------------
// C[N][M] = act( A[N][K] @ B[Mp][K]^T + bias[M] ); K mult of 64, N mult of 128.
__global__ __launch_bounds__(256) void k_mfma_gemm(
    const u16* __restrict__ A, const u16* __restrict__ B,
    const float* __restrict__ bias,
    float* __restrict__ outf, u16* __restrict__ outb,
    int N, int K, int M, int act)
{
  __shared__ u16 As[128 * 64];
  __shared__ u16 Bs[128 * 64];
  const int bn = blockIdx.y * 128;
  const int bm = blockIdx.x * 128;
  const int tid = threadIdx.x;
  const int w = tid >> 6, lane = tid & 63;
  const int wr = w >> 1, wc = w & 1;

  f32x4 acc[4][4];
#pragma unroll
  for (int i = 0; i < 4; ++i)
#pragma unroll
    for (int j = 0; j < 4; ++j) acc[i][j] = (f32x4){0.f, 0.f, 0.f, 0.f};

  const int lr8 = lane >> 3;
  const int lc8 = lane & 7;

  for (int kt = 0; kt < K; kt += 64) {
    __syncthreads();
#pragma unroll
    for (int i = 0; i < 4; ++i) {
      int r0 = (w * 4 + i) * 8;
      int r = r0 + lr8;
      int c = lc8 ^ (r & 7);
      const u16* ga = A + (size_t)(bn + r) * K + kt + c * 8;
      const u16* gb = B + (size_t)(bm + r) * K + kt + c * 8;
      __builtin_amdgcn_global_load_lds((const __attribute__((address_space(1))) u32*)ga,
                                       (__attribute__((address_space(3))) u32*)(As + r0 * 64), 16, 0, 0);
      __builtin_amdgcn_global_load_lds((const __attribute__((address_space(1))) u32*)gb,
                                       (__attribute__((address_space(3))) u32*)(Bs + r0 * 64), 16, 0, 0);
    }
    __syncthreads();

    const int m16 = lane & 15, q = lane >> 4;
#pragma unroll
    for (int kk = 0; kk < 2; ++kk) {
      bf16x8 af[4], bfr[4];
#pragma unroll
      for (int i = 0; i < 4; ++i) {
        int ra = wr * 64 + i * 16 + m16;
        af[i] = *(const bf16x8*)&As[ra * 64 + ((kk * 4 + q) ^ (ra & 7)) * 8];
        int rb = wc * 64 + i * 16 + m16;
        bfr[i] = *(const bf16x8*)&Bs[rb * 64 + ((kk * 4 + q) ^ (rb & 7)) * 8];
      }
#pragma unroll
      for (int i = 0; i < 4; ++i)
#pragma unroll
        for (int j = 0; j < 4; ++j)
          acc[i][j] = __builtin_amdgcn_mfma_f32_16x16x32_bf16(af[i], bfr[j], acc[i][j], 0, 0, 0);
    }
  }

  const int m16 = lane & 15, q = lane >> 4;
#pragma unroll
  for (int i = 0; i < 4; ++i) {
#pragma unroll
    for (int j = 0; j < 4; ++j) {
      int col = bm + wc * 64 + j * 16 + m16;
      if (col >= M) continue;
      float bs = bias[col];
#pragma unroll
      for (int p = 0; p < 4; ++p) {
        int row = bn + wr * 64 + i * 16 + q * 4 + p;
        float v = acc[i][j][p] + bs;
        if (act) v = (v > 0.f) ? v : expm1f(v);
        if (outf) outf[(size_t)row * M + col] = v;
        else      outb[(size_t)row * M + col] = f2bf(v);
      }
    }
  }
}

// ---------------- loss ----------------
__global__ __launch_bounds__(256) void k_loss(
    const float* __restrict__ obs, const float* __restrict__ action,
    const float* __restrict__ p_obs, const float* __restrict__ p_act,
    const float* __restrict__ p_rew, double* __restrict__ acc)
{
  const long long n1 = (long long)TT * BB * OBS;
  const long long n2 = (long long)TT * BB * ACT;
  const long long n  = n1 + n2 + n2;
  const float C = 0.91893853320467274178f;  // 0.5*ln(2*pi)
  double s = 0.0;
  for (long long idx = (long long)blockIdx.x * blockDim.x + threadIdx.x; idx < n;
       idx += (long long)gridDim.x * blockDim.x) {
    float d;
    if (idx < n1) {
      d = obs[idx] - p_obs[idx];
    } else if (idx < n1 + n2) {
      long long i = idx - n1;
      d = action[i] - p_act[i];
    } else {
      long long i = idx - n1 - n2;
      d = action[i] - p_rew[i >> 5];
    }
    s += (double)(0.5f * d * d + C);
  }
  __shared__ double red[256];
  red[threadIdx.x] = s;
  __syncthreads();
  for (int off = 128; off > 0; off >>= 1) {
    if ((int)threadIdx.x < off) red[threadIdx.x] += red[threadIdx.x + off];
    __syncthreads();
  }
  if (threadIdx.x == 0) atomicAdd(acc, red[0]);
}

__global__ void k_finalize(const double* __restrict__ acc, float* __restrict__ out) {
  if (threadIdx.x == 0) out[0] = (float)(acc[0] / (double)(TT * BB));
}

// ---------------- launch ----------------

extern "C" void kernel_launch(void* const* d_in, const int* in_sizes, int n_in,
                              void* d_out, int out_size, void* d_ws, size_t ws_size,
                              hipStream_t stream) {
  const float* obs    = (const float*)d_in[0];
  const float* action = (const float*)d_in[1];
  const float* w_ih = (const float*)d_in[3];
  const float* w_hh = (const float*)d_in[4];
  const float* b_ih = (const float*)d_in[5];
  const float* b_hh = (const float*)d_in[6];
  const float* hw[9] = {(const float*)d_in[7],  (const float*)d_in[9],  (const float*)d_in[11],
                        (const float*)d_in[13], (const float*)d_in[15], (const float*)d_in[17],
                        (const float*)d_in[19], (const float*)d_in[21], (const float*)d_in[23]};
  const float* hb[9] = {(const float*)d_in[8],  (const float*)d_in[10], (const float*)d_in[12],
                        (const float*)d_in[14], (const float*)d_in[16], (const float*)d_in[18],
                        (const float*)d_in[20], (const float*)d_in[22], (const float*)d_in[24]};
  const int hM[9]  = {512, 512, 128, 512, 512, 32, 512, 512, 1};
  const int hMp[9] = {512, 512, 128, 512, 512, 128, 512, 512, 128};

  float* out     = (float*)d_out;
  float* pre_obs = out + 1;
  float* pre_act = pre_obs + (size_t)TT * BB * OBS;
  float* pre_rew = pre_act + (size_t)TT * BB * ACT;

  // ---- workspace ----
  char* ws = (char*)d_ws;
  size_t off = 0;
  auto alloc = [&](size_t bytes) { void* p = ws + off; off = (off + bytes + 255) & ~(size_t)255; return p; };
  double* acc  = (double*)alloc(256);
  int* bars    = (int*)alloc(16 * 256);           // padded counters
  u32* zerobuf = (u32*)alloc(1024);
  u16* Wr  = (u16*)alloc((size_t)512 * 704 * 2);
  u16* Wz  = (u16*)alloc((size_t)512 * 704 * 2);
  u16* Wnh = (u16*)alloc((size_t)512 * 512 * 2);
  u16* Wni = (u16*)alloc((size_t)512 * 192 * 2);
  float* bias4 = (float*)alloc(2048 * 4);
  u16* headb[9];
  for (int i = 0; i < 9; ++i) headb[i] = (u16*)alloc((size_t)hMp[i] * 512 * 2);
  float* h32c = (float*)alloc((size_t)BB * 512 * 4);
  u16* Xb     = (u16*)alloc((size_t)TT * BB * 160 * 2);   // 41.9 MB
  const size_t fixed = off;

  int TC = 512;
  while (TC > 8 && fixed + 3ull * TC * BB * 512 * 2ull + (1u << 20) > ws_size) TC >>= 1;
  u16* hs_chunk = (u16*)alloc((size_t)TC * BB * 512 * 2);
  u16* tmp1b    = (u16*)alloc((size_t)TC * BB * 512 * 2);
  u16* tmp2b    = (u16*)alloc((size_t)TC * BB * 512 * 2);
  const int CH = TC * BB;
  const int NCH = TT / TC;

  // ---- setup ----
  k_init<<<1, 256, 0, stream>>>(acc, bars, zerobuf);
  k_prep_w<<<512, 256, 0, stream>>>(w_ih, w_hh, b_ih, b_hh, Wr, Wz, Wnh, Wni, bias4);
  for (int i = 0; i < 9; ++i)
    k_convert_pad<<<512, 256, 0, stream>>>(hw[i], headb[i], hM[i], 512, hMp[i], 512);
  k_pack_x<<<4096, 256, 0, stream>>>(obs, action, Xb);

  for (int c = 0; c < NCH; ++c) {
    k_gru_seq<<<dim3(16, 16), 256, 0, stream>>>(
        Wr, Wz, Wnh, Wni, bias4, Xb, hs_chunk, h32c, (const u16*)zerobuf, bars, c * TC, TC);
    for (int h = 0; h < 3; ++h) {
      int M2 = hM[h * 3 + 2], Mp2 = hMp[h * 3 + 2];
      float* outp = (h == 0) ? pre_obs + (size_t)c * CH * OBS
                  : (h == 1) ? pre_act + (size_t)c * CH * ACT
                             : pre_rew + (size_t)c * CH;
      k_mfma_gemm<<<dim3(4, CH / 128), 256, 0, stream>>>(
          hs_chunk, headb[h * 3 + 0], hb[h * 3 + 0], nullptr, tmp1b, CH, 512, 512, 1);
      k_mfma_gemm<<<dim3(4, CH / 128), 256, 0, stream>>>(
          tmp1b, headb[h * 3 + 1], hb[h * 3 + 1], nullptr, tmp2b, CH, 512, 512, 1);
      k_mfma_gemm<<<dim3(Mp2 / 128, CH / 128), 256, 0, stream>>>(
          tmp2b, headb[h * 3 + 2], hb[h * 3 + 2], outp, nullptr, CH, 512, M2, 0);
    }
  }

  k_loss<<<2048, 256, 0, stream>>>(obs, action, pre_obs, pre_act, pre_rew, acc);
  k_finalize<<<1, 64, 0, stream>>>(acc, out);
}